// Round 3
// baseline (26125.076 us; speedup 1.0000x reference)
//
#include <hip/hip_runtime.h>
#include <math.h>
#include <stdint.h>

// Problem: x[64][512][512] fp32, W[1024][2048] fp32, b[2048] fp32 -> out[64][512][512]
// z = [h,x]@W + b ; f,i,o,cb = split(z,4); c' = sig(f)*c + sig(i)*cb ; h' = sig(o)*c'
#define Bz 64
#define Tz 512
#define Dz 512
#define Hz 512

// storage col n = bx*8 + cc, cc = g*2 + j  <->  original W col = g*512 + bx*2 + j
__device__ __forceinline__ int wcol_of(int bx, int cc) {
    return (cc >> 1) * 512 + bx * 2 + (cc & 1);
}

// ===================== workspace =====================
//   ghb   : float [2][64][512]  (256 KB) double-buffered h
//   arrive: int   [513]         (2 KB)   per-step arrival counters
#define GHB_FLOATS (2 * 64 * 512)
#define ARR_INTS   513
#define FUSED_WS_BYTES ((size_t)GHB_FLOATS * 4 + (size_t)ARR_INTS * 4)

// ===================== LDS layout (floats), static pool =====================
#define A_STRIDE  516
#define W_STRIDE  1044
#define WT_OFF    16512    /* 32*516 */
#define ZSC_OFF   24864    /* +8*1044 */
#define ZRED_OFF  33184    /* +16*520 */
#define POOL_FL   33696    /* +512 ; 134,784 B < 163,840 B */

__global__ __launch_bounds__(256) void zero_init(int* __restrict__ p, int n) {
    int i = blockIdx.x * 256 + threadIdx.x;
    if (i < n) p[i] = 0;
}

__device__ __forceinline__ void gload_lds16(const float* g, float* l) {
    __builtin_amdgcn_global_load_lds((const __attribute__((address_space(1))) void*)g,
                                     (__attribute__((address_space(3))) void*)l,
                                     16, 0, 0);
}

// stage 32 rows x 512 floats into A; wave wid stages rows [wid*4, wid*4+4)
__device__ __forceinline__ void stage32(const float* __restrict__ src_base,
                                        size_t row_stride, float* __restrict__ A,
                                        int wid, int lane) {
#pragma unroll
    for (int rr = 0; rr < 4; ++rr) {
        int r = wid * 4 + rr;
#pragma unroll
        for (int half = 0; half < 2; ++half)
            gload_lds16(src_base + (size_t)r * row_stride + half * 256 + lane * 4,
                        A + r * A_STRIDE + half * 256);
    }
}

// per-thread GEMM over one 32-row A half: acc[i][c] += A[sh+8i][k] * wt[2c2+c][ksrc+k]
__device__ __forceinline__ void gemm_half(const float* __restrict__ A,
                                          const float* __restrict__ wt,
                                          int ksrc, int kq, int sh, int c2,
                                          float acc[4][2]) {
    const int kb = kq * 32;
    const float* w0p = wt + (2 * c2)     * W_STRIDE + ksrc + kb;
    const float* w1p = wt + (2 * c2 + 1) * W_STRIDE + ksrc + kb;
#pragma unroll
    for (int kk = 0; kk < 32; kk += 4) {
        float4 w0 = *(const float4*)(w0p + kk);
        float4 w1 = *(const float4*)(w1p + kk);
#pragma unroll
        for (int i = 0; i < 4; ++i) {
            float4 a = *(const float4*)(A + (sh + 8 * i) * A_STRIDE + kb + kk);
            acc[i][0] += a.x * w0.x + a.y * w0.y + a.z * w0.z + a.w * w0.w;
            acc[i][1] += a.x * w1.x + a.y * w1.y + a.z * w1.z + a.w * w1.w;
        }
    }
}

// --- fused persistent LSTM: 256 blocks (1/CU, 134.8 KB static LDS) x 512 thr ---
// block bx owns h-cols {2bx, 2bx+1} x 4 gates (8 z-cols); full W cols in LDS.
// Per step: x-GEMM (2 halves, barrier-independent) -> wait h_t -> h-GEMM ->
// reduce -> gates (c in regs) -> write h_{t+1} -> signal arrive[t+1].
__global__ void __launch_bounds__(512) lstm_fused(const float* __restrict__ x,
                                                  const float* __restrict__ W,
                                                  const float* __restrict__ bias,
                                                  float* __restrict__ ghb,
                                                  int* __restrict__ arrive,
                                                  float* __restrict__ out) {
    __shared__ float pool[POOL_FL];
    float* A    = pool;             // [32][516] staged rows (h or x, one half)
    float* wt   = pool + WT_OFF;    // [8][1044] W cols: h-part [0,512), x-part [512,1024)
    float* zsc  = pool + ZSC_OFF;   // [16][520] K-split partials
    float* zred = pool + ZRED_OFF;  // [512]

    const int bx   = blockIdx.x;    // 0..255
    const int tid  = threadIdx.x;
    const int lane = tid & 63;
    const int wid  = tid >> 6;      // 8 waves

    // resident W slice: wt[cc][k] = W[k][wcol_of(bx,cc)], k in [0,1024)
    for (int i = tid; i < 8 * 1024; i += 512) {
        int cc = i >> 10, k = i & 1023;
        wt[cc * W_STRIDE + k] = W[(size_t)k * 2048 + wcol_of(bx, cc)];
    }
    float c_reg = 0.0f;             // persistent cell state (tid<128 owns (s,j))
    __syncthreads();

    // GEMM thread decomposition
    const int c2 = tid & 3;          // col pair -> cc {2c2, 2c2+1}
    const int sh = (tid >> 2) & 7;   // rows {sh, sh+8, sh+16, sh+24} within half
    const int kq = tid >> 5;         // 0..15, K-span 32

    for (int t = 0; t < Tz; ++t) {
        float accA[4][2] = {{0.f,0.f},{0.f,0.f},{0.f,0.f},{0.f,0.f}};
        float accB[4][2] = {{0.f,0.f},{0.f,0.f},{0.f,0.f},{0.f,0.f}};

        // ---- x phases (no dependency on h_t; overlaps other blocks' tails) ----
        const float* xt = x + (size_t)t * Dz;
        stage32(xt, (size_t)Tz * Dz, A, wid, lane);                   // rows 0..31
        __syncthreads();
        gemm_half(A, wt, 512, kq, sh, c2, accA);
        __syncthreads();
        stage32(xt + (size_t)32 * Tz * Dz, (size_t)Tz * Dz, A, wid, lane);
        __syncthreads();
        gemm_half(A, wt, 512, kq, sh, c2, accB);
        __syncthreads();

        // ---- wait for h_t (written at end of step t-1 by all blocks) ----
        if (t > 0) {
            if (tid == 0) {
                int iters = 0;
                while (__hip_atomic_load(&arrive[t], __ATOMIC_RELAXED,
                                         __HIP_MEMORY_SCOPE_AGENT) < 256) {
                    __builtin_amdgcn_s_sleep(1);
                    if (++iters >= 100000) break;   // safety: no hangs, ever
                }
                __threadfence();                    // acquire: invalidate stale h
            }
            __syncthreads();
        }

        // ---- h phases ----
        const float* hsrc = ghb + (size_t)(t & 1) * (64 * 512);
        stage32(hsrc, 512, A, wid, lane);                              // rows 0..31
        __syncthreads();
        gemm_half(A, wt, 0, kq, sh, c2, accA);
        __syncthreads();
        stage32(hsrc + 32 * 512, 512, A, wid, lane);
        __syncthreads();
        gemm_half(A, wt, 0, kq, sh, c2, accB);

        // ---- K-split partials -> LDS ----
#pragma unroll
        for (int i = 0; i < 4; ++i) {
            *(float2*)(zsc + kq * 520 + (sh + 8 * i) * 8 + 2 * c2) =
                make_float2(accA[i][0], accA[i][1]);
            *(float2*)(zsc + kq * 520 + (32 + sh + 8 * i) * 8 + 2 * c2) =
                make_float2(accB[i][0], accB[i][1]);
        }
        __syncthreads();

        // ---- reduce 16 partials + bias ----
        {
            float zs = 0.f;
#pragma unroll
            for (int q = 0; q < 16; ++q) zs += zsc[q * 520 + tid];
            int cc = tid & 7;
            zred[tid] = zs + bias[wcol_of(bx, cc)];
        }
        __syncthreads();

        // ---- gates: tid<128 owns (s = tid>>1, j = tid&1); c stays in register ----
        if (tid < 128) {
            int s = tid >> 1, j = tid & 1;
            float zf = zred[s * 8 + 0 + j];
            float zi = zred[s * 8 + 2 + j];
            float zo = zred[s * 8 + 4 + j];
            float zc = zred[s * 8 + 6 + j];
            float sf = 1.f / (1.f + expf(-zf));
            float si = 1.f / (1.f + expf(-zi));
            float so = 1.f / (1.f + expf(-zo));
            float cnew = sf * c_reg + si * zc;
            c_reg = cnew;
            float h = so * cnew;
            int hc = bx * 2 + j;
            ghb[(size_t)((t + 1) & 1) * (64 * 512) + s * 512 + hc] = h;
            out[(size_t)s * (Tz * Hz) + (size_t)t * Hz + hc] = h;
        }
        __syncthreads();            // drains vmcnt: h stores in L2 before release

        if (tid == 0 && t + 1 < Tz) {
            __threadfence();        // release: h_{t+1} visible device-wide
            atomicAdd(&arrive[t + 1], 1);
        }
    }
}

// ===================== LEGACY PATH (verified, kept as emergency fallback) =====================
#define WB_FLOATS   (64*1024*32)
#define HBUF_FLOATS (64*512)

__global__ __launch_bounds__(256) void zero_ws(float* __restrict__ p, int n) {
    int i = blockIdx.x * 256 + threadIdx.x;
    if (i < n) p[i] = 0.0f;
}

__global__ __launch_bounds__(256) void prep_w(const float* __restrict__ W,
                                              float* __restrict__ Wb) {
    int k = blockIdx.x;
    for (int it = 0; it < 8; ++it) {
        int col = it * 256 + threadIdx.x;
        float v = W[(size_t)k * 2048 + col];
        int g = col >> 9, rem = col & 511;
        int cg = rem >> 3, hc = rem & 7;
        int c = g * 8 + hc;
        Wb[((size_t)cg * 1024 + k) * 32 + c] = v;
    }
}

__global__ __launch_bounds__(256) void lstm_step(
    const float* __restrict__ x, const float* __restrict__ bias,
    const float* __restrict__ Wb, const float* __restrict__ hbr,
    float* __restrict__ hbw, float* __restrict__ cbuf,
    float* __restrict__ out, int t)
{
    const int cg  = blockIdx.x;
    const int sg  = blockIdx.y;
    const int tid = threadIdx.x;

    __shared__ float As[16 * 1028];
    __shared__ float zpart[8 * 512];
    __shared__ float zred[512];

    for (int it = 0; it < 16; ++it) {
        int fi = it * 256 + tid;
        int s  = fi >> 8;
        int k  = (fi & 255) * 4;
        const float* src;
        if (k < 512) src = hbr + (sg * 16 + s) * 512 + k;
        else         src = x + (size_t)(sg * 16 + s) * Tz * Dz + (size_t)t * Dz + (k - 512);
        float4 v = *(const float4*)src;
        *(float4*)(As + s * 1028 + k) = v;
    }
    __syncthreads();

    const int ct = tid & 7;
    const int st = (tid >> 3) & 3;
    const int kw = tid >> 5;

    float acc[4][4];
#pragma unroll
    for (int i = 0; i < 4; ++i)
#pragma unroll
        for (int j = 0; j < 4; ++j) acc[i][j] = 0.0f;

    const float* wp = Wb + (size_t)cg * 1024 * 32 + (size_t)(kw * 128) * 32 + ct * 4;
    const float* ap = As + st * 4 * 1028 + kw * 128;

#pragma unroll 4
    for (int kk = 0; kk < 128; kk += 4) {
        float4 w0 = *(const float4*)(wp + (kk + 0) * 32);
        float4 w1 = *(const float4*)(wp + (kk + 1) * 32);
        float4 w2 = *(const float4*)(wp + (kk + 2) * 32);
        float4 w3 = *(const float4*)(wp + (kk + 3) * 32);
        float4 a0 = *(const float4*)(ap + 0 * 1028 + kk);
        float4 a1 = *(const float4*)(ap + 1 * 1028 + kk);
        float4 a2 = *(const float4*)(ap + 2 * 1028 + kk);
        float4 a3 = *(const float4*)(ap + 3 * 1028 + kk);
#define FMA_ROW(i, ai)                                              \
        acc[i][0] += ai.x * w0.x + ai.y * w1.x + ai.z * w2.x + ai.w * w3.x; \
        acc[i][1] += ai.x * w0.y + ai.y * w1.y + ai.z * w2.y + ai.w * w3.y; \
        acc[i][2] += ai.x * w0.z + ai.y * w1.z + ai.z * w2.z + ai.w * w3.z; \
        acc[i][3] += ai.x * w0.w + ai.y * w1.w + ai.z * w2.w + ai.w * w3.w;
        FMA_ROW(0, a0)
        FMA_ROW(1, a1)
        FMA_ROW(2, a2)
        FMA_ROW(3, a3)
#undef FMA_ROW
    }

#pragma unroll
    for (int i = 0; i < 4; ++i) {
        float4 v = make_float4(acc[i][0], acc[i][1], acc[i][2], acc[i][3]);
        *(float4*)(zpart + kw * 512 + (st * 4 + i) * 32 + ct * 4) = v;
    }
    __syncthreads();

    {
        int o = tid * 2;
        float z0 = 0.0f, z1 = 0.0f;
#pragma unroll
        for (int w = 0; w < 8; ++w) {
            float2 v = *(const float2*)(zpart + w * 512 + o);
            z0 += v.x; z1 += v.y;
        }
        *(float2*)(zred + o) = make_float2(z0, z1);
    }
    __syncthreads();

    if (tid < 128) {
        int s  = tid >> 3;
        int hc = tid & 7;
        int colb = cg * 8 + hc;
        float zf = zred[s * 32 + hc]       + bias[colb];
        float zi = zred[s * 32 + 8 + hc]   + bias[512 + colb];
        float zo = zred[s * 32 + 16 + hc]  + bias[1024 + colb];
        float zc = zred[s * 32 + 24 + hc]  + bias[1536 + colb];

        int cidx = (sg * 64 + cg) * 128 + tid;
        float cold = cbuf[cidx];
        float sf = 1.0f / (1.0f + expf(-zf));
        float si = 1.0f / (1.0f + expf(-zi));
        float so = 1.0f / (1.0f + expf(-zo));
        float cnew = sf * cold + si * zc;
        float h = so * cnew;
        cbuf[cidx] = cnew;

        hbw[(sg * 16 + s) * 512 + colb] = h;
        out[(size_t)(sg * 16 + s) * Tz * Hz + (size_t)t * Hz + colb] = h;
    }
}

static void run_legacy(const float* x, const float* W, const float* bias,
                       float* out, void* d_ws, hipStream_t stream) {
    char* ws = (char*)d_ws;
    float* Wb   = (float*)ws;
    float* hbuf = (float*)(ws + (size_t)WB_FLOATS * 4);
    float* cbuf = hbuf + 2 * HBUF_FLOATS;

    zero_ws<<<384, 256, 0, stream>>>(hbuf, 98304);
    prep_w<<<1024, 256, 0, stream>>>(W, Wb);

    for (int t = 0; t < Tz; ++t) {
        float* hr = hbuf + (t & 1) * HBUF_FLOATS;
        float* hw = hbuf + ((t + 1) & 1) * HBUF_FLOATS;
        lstm_step<<<dim3(64, 4), 256, 0, stream>>>(x, bias, Wb, hr, hw, cbuf, out, t);
    }
}

// ===================== launcher =====================
extern "C" void kernel_launch(void* const* d_in, const int* in_sizes, int n_in,
                              void* d_out, int out_size, void* d_ws, size_t ws_size,
                              hipStream_t stream) {
    const float* x    = (const float*)d_in[0];
    const float* W    = (const float*)d_in[1];
    const float* bias = (const float*)d_in[2];
    float* out = (float*)d_out;

    if (ws_size < FUSED_WS_BYTES) {          // cannot happen in practice (264 KB)
        run_legacy(x, W, bias, out, d_ws, stream);
        return;
    }

    float* ghb  = (float*)d_ws;
    int* arrive = (int*)(ghb + GHB_FLOATS);

    zero_init<<<dim3((GHB_FLOATS + ARR_INTS + 255) / 256), 256, 0, stream>>>(
        (int*)ghb, GHB_FLOATS + ARR_INTS);
    lstm_fused<<<dim3(256), dim3(512), 0, stream>>>(x, W, bias, ghb, arrive, out);
}

// Round 4
// 12597.418 us; speedup vs baseline: 2.0738x; 2.0738x over previous
//
#include <hip/hip_runtime.h>
#include <math.h>
#include <stdint.h>

// Problem: x[64][512][512] fp32, W[1024][2048] fp32, b[2048] fp32 -> out[64][512][512]
// z = [h,x]@W + b ; f,i,o,cb = split(z,4); c' = sig(f)*c + sig(i)*cb ; h' = sig(o)*c'
#define Bz 64
#define Tz 512
#define Dz 512
#define Hz 512

// storage col n = bx*8 + cc, cc = g*2 + j  <->  original W col = g*512 + bx*2 + j
__device__ __forceinline__ int wcol_of(int bx, int cc) {
    return (cc >> 1) * 512 + bx * 2 + (cc & 1);
}

// ===================== workspace (tiny) =====================
//   arrive : int [516]   per-step arrival counters (padded for 16B alignment of zbuf)
//   zbuf   : float [512] zeros (h_0 staging source)
#define ARR_INTS 516
#define ZBUF_FL  512
#define FUSED_WS_BYTES ((size_t)(ARR_INTS + ZBUF_FL) * 4)

// ===================== LDS =====================
#define A_ST    1028                 /* row stride: 1024 k + pad (16B-aligned rows) */
#define A_FL    (16 * A_ST)          /* one quarter: 16 rows x 1024 k              */
#define ZSC_ST  132
#define POOL_FL (2 * A_FL + 8 * ZSC_ST)   /* 33952 fl = 135,808 B (<160 KB)        */

__global__ __launch_bounds__(256) void zero_init(int* __restrict__ p, int n) {
    int i = blockIdx.x * 256 + threadIdx.x;
    if (i < n) p[i] = 0;
}

__device__ __forceinline__ void gload_lds16(const float* g, float* l) {
    __builtin_amdgcn_global_load_lds((const __attribute__((address_space(1))) void*)g,
                                     (__attribute__((address_space(3))) void*)l,
                                     16, 0, 0);
}

// stage one 16-row quarter of A: rows s=q*16+wid*2+{0,1}; 8 gload_lds per wave.
// A row layout: [0..511] = h_t (from out[s][t-1][.]; zbuf at t==0), [512..1023] = x[s][t][.]
__device__ __forceinline__ void stage_q(float* __restrict__ Ab,
                                        const float* __restrict__ x,
                                        const float* __restrict__ out,
                                        const float* __restrict__ zbuf,
                                        int t, int q, int wid, int lane) {
#pragma unroll
    for (int rr = 0; rr < 2; ++rr) {
        int r = wid * 2 + rr;
        int s = q * 16 + r;
        const float* xs = x + (size_t)s * (Tz * Dz) + (size_t)t * Dz;
        const float* hs = (t == 0) ? zbuf
                        : out + (size_t)s * (Tz * Hz) + (size_t)(t - 1) * Hz;
        float* arow = Ab + r * A_ST;
        gload_lds16(hs + lane * 4,       arow);
        gload_lds16(hs + 256 + lane * 4, arow + 256);
        gload_lds16(xs + lane * 4,       arow + 512);
        gload_lds16(xs + 256 + lane * 4, arow + 768);
    }
}

// one quarter: wait(stage done) -> barrier -> GEMM (W in regs) -> in-wave reduce
// -> zsc cross-wave partials -> barrier -> gates for this quarter (reg-only).
template <int QQ, bool LAST>
__device__ __forceinline__ void quarter_body(const float* __restrict__ Ab,
                                             float* __restrict__ zsc,
                                             int tid, int lane, int wid, int rg, int koff,
                                             const float (&wreg)[8][8],
                                             const float (&bias_r)[4],
                                             float& c_reg, float& h_reg) {
    if (LAST) { asm volatile("s_waitcnt vmcnt(0)" ::: "memory"); }
    else      { asm volatile("s_waitcnt vmcnt(8)" ::: "memory"); }
    __builtin_amdgcn_s_barrier();
    __builtin_amdgcn_sched_barrier(0);

    // ---- GEMM: 4 rows x 8 cols x 8 K per thread; A from LDS, W from registers ----
    float acc[4][8];
#pragma unroll
    for (int rr = 0; rr < 4; ++rr) {
        const float* ar = Ab + (rg * 4 + rr) * A_ST + koff;
        float4 a0 = *(const float4*)(ar);
        float4 a1 = *(const float4*)(ar + 4);
#pragma unroll
        for (int c = 0; c < 8; ++c) {
            acc[rr][c] = a0.x * wreg[0][c] + a0.y * wreg[1][c]
                       + a0.z * wreg[2][c] + a0.w * wreg[3][c]
                       + a1.x * wreg[4][c] + a1.y * wreg[5][c]
                       + a1.z * wreg[6][c] + a1.w * wreg[7][c];
        }
    }

    // ---- in-wave reduce over kql (lane bits 0-3) ----
#pragma unroll
    for (int m = 1; m < 16; m <<= 1)
#pragma unroll
        for (int rr = 0; rr < 4; ++rr)
#pragma unroll
            for (int c = 0; c < 8; ++c)
                acc[rr][c] += __shfl_xor(acc[rr][c], m, 64);

    // ---- cross-wave partials: one writer lane per kql-group ----
    if ((lane & 15) == 0) {
#pragma unroll
        for (int rr = 0; rr < 4; ++rr) {
            int cell = (rg * 4 + rr) * 8;
            *(float4*)(zsc + wid * ZSC_ST + cell) =
                make_float4(acc[rr][0], acc[rr][1], acc[rr][2], acc[rr][3]);
            *(float4*)(zsc + wid * ZSC_ST + cell + 4) =
                make_float4(acc[rr][4], acc[rr][5], acc[rr][6], acc[rr][7]);
        }
    }
    asm volatile("s_waitcnt lgkmcnt(0)" ::: "memory");
    __builtin_amdgcn_s_barrier();
    __builtin_amdgcn_sched_barrier(0);

    // ---- gates for this quarter's 16 rows (thread tid = s*2+j, s in quarter) ----
    if (tid < 128 && (tid >> 5) == QQ) {
        int lr = (tid >> 1) & 15, j = tid & 1;
        float zg[4];
#pragma unroll
        for (int g = 0; g < 4; ++g) {
            float zz = bias_r[g];
#pragma unroll
            for (int kw = 0; kw < 8; ++kw)
                zz += zsc[kw * ZSC_ST + lr * 8 + g * 2 + j];
            zg[g] = zz;
        }
        float sf = 1.f / (1.f + expf(-zg[0]));
        float si = 1.f / (1.f + expf(-zg[1]));
        float so = 1.f / (1.f + expf(-zg[2]));
        c_reg = sf * c_reg + si * zg[3];
        h_reg = so * c_reg;    // store deferred to end-of-step (uniform vmcnt)
    }
}

// --- persistent fused LSTM: 256 blocks (1/CU, 135.8 KB static LDS) x 512 thr ---
// block bx owns 8 z-cols (2 h-cols x 4 gates) for ALL 64 batch rows.
// W slice lives in registers (64/thread). h exchanged THROUGH out[] (unique addr
// per t => no stale L2 lines; producers write-through via agent-scope stores;
// consumers' global_load_lds cold-miss L3). NO fences anywhere.
__global__ void __launch_bounds__(512) lstm_fused2(
        const float* __restrict__ x, const float* __restrict__ W,
        const float* __restrict__ bias, int* __restrict__ arrive,
        const float* __restrict__ zbuf, float* __restrict__ out) {
    __shared__ float pool[POOL_FL];
    float* A0  = pool;
    float* A1  = pool + A_FL;
    float* zsc = pool + 2 * A_FL;

    const int bx   = blockIdx.x;    // 0..255
    const int tid  = threadIdx.x;
    const int lane = tid & 63;
    const int wid  = tid >> 6;                  // 8 waves
    const int rg   = lane >> 4;                 // row-group (4 rows)
    const int kq   = wid * 16 + (lane & 15);    // 0..127, K-span 8
    const int koff = kq * 8;

    // ---- one-time: W slice into registers (8 K x 8 cols per thread) ----
    float wreg[8][8];
#pragma unroll
    for (int kk = 0; kk < 8; ++kk)
#pragma unroll
        for (int c = 0; c < 8; ++c)
            wreg[kk][c] = W[(size_t)(koff + kk) * 2048 + wcol_of(bx, c)];

    float bias_r[4] = {0.f, 0.f, 0.f, 0.f};
    if (tid < 128) {
        int j = tid & 1;
#pragma unroll
        for (int g = 0; g < 4; ++g) bias_r[g] = bias[wcol_of(bx, g * 2 + j)];
    }
    const int s_own = tid >> 1, j_own = tid & 1;
    float c_reg = 0.f, h_reg = 0.f;

    for (int t = 0; t < Tz; ++t) {
        // ---- wait for all of h_t (written during step t-1) ----
        if (t > 0) {
            if (tid == 0) {
                int it = 0;
                while (__hip_atomic_load(arrive + (t - 1), __ATOMIC_RELAXED,
                                         __HIP_MEMORY_SCOPE_AGENT) < 256) {
                    __builtin_amdgcn_s_sleep(2);
                    if (++it > 20000) break;   // safety: wrong-results > hang
                }
            }
            __builtin_amdgcn_s_barrier();
            __builtin_amdgcn_sched_barrier(0);
        }

        // ---- 4 row-quarters, double-buffered, counted vmcnt(8) ----
        stage_q(A0, x, out, zbuf, t, 0, wid, lane);
        stage_q(A1, x, out, zbuf, t, 1, wid, lane);
        quarter_body<0, false>(A0, zsc, tid, lane, wid, rg, koff, wreg, bias_r, c_reg, h_reg);
        stage_q(A0, x, out, zbuf, t, 2, wid, lane);
        quarter_body<1, false>(A1, zsc, tid, lane, wid, rg, koff, wreg, bias_r, c_reg, h_reg);
        stage_q(A1, x, out, zbuf, t, 3, wid, lane);
        quarter_body<2, false>(A0, zsc, tid, lane, wid, rg, koff, wreg, bias_r, c_reg, h_reg);
        quarter_body<3, true >(A1, zsc, tid, lane, wid, rg, koff, wreg, bias_r, c_reg, h_reg);

        // ---- publish h_{t+1}: write-through store into out, then signal ----
        if (tid < 128) {
            __hip_atomic_store(out + (size_t)s_own * (Tz * Hz) + (size_t)t * Hz
                                   + bx * 2 + j_own,
                               h_reg, __ATOMIC_RELAXED, __HIP_MEMORY_SCOPE_AGENT);
        }
        asm volatile("s_waitcnt vmcnt(0)" ::: "memory");
        __builtin_amdgcn_s_barrier();
        __builtin_amdgcn_sched_barrier(0);
        if (tid == 0)
            __hip_atomic_fetch_add(arrive + t, 1, __ATOMIC_RELAXED,
                                   __HIP_MEMORY_SCOPE_AGENT);
    }
}

// ===================== LEGACY PATH (verified fallback, needs 8.6 MB ws) =====================
#define WB_FLOATS   (64*1024*32)
#define HBUF_FLOATS (64*512)

__global__ __launch_bounds__(256) void zero_ws(float* __restrict__ p, int n) {
    int i = blockIdx.x * 256 + threadIdx.x;
    if (i < n) p[i] = 0.0f;
}

__global__ __launch_bounds__(256) void prep_w(const float* __restrict__ W,
                                              float* __restrict__ Wb) {
    int k = blockIdx.x;
    for (int it = 0; it < 8; ++it) {
        int col = it * 256 + threadIdx.x;
        float v = W[(size_t)k * 2048 + col];
        int g = col >> 9, rem = col & 511;
        int cg = rem >> 3, hc = rem & 7;
        int c = g * 8 + hc;
        Wb[((size_t)cg * 1024 + k) * 32 + c] = v;
    }
}

__global__ __launch_bounds__(256) void lstm_step(
    const float* __restrict__ x, const float* __restrict__ bias,
    const float* __restrict__ Wb, const float* __restrict__ hbr,
    float* __restrict__ hbw, float* __restrict__ cbuf,
    float* __restrict__ out, int t)
{
    const int cg  = blockIdx.x;
    const int sg  = blockIdx.y;
    const int tid = threadIdx.x;

    __shared__ float As[16 * 1028];
    __shared__ float zpart[8 * 512];
    __shared__ float zred[512];

    for (int it = 0; it < 16; ++it) {
        int fi = it * 256 + tid;
        int s  = fi >> 8;
        int k  = (fi & 255) * 4;
        const float* src;
        if (k < 512) src = hbr + (sg * 16 + s) * 512 + k;
        else         src = x + (size_t)(sg * 16 + s) * Tz * Dz + (size_t)t * Dz + (k - 512);
        float4 v = *(const float4*)src;
        *(float4*)(As + s * 1028 + k) = v;
    }
    __syncthreads();

    const int ct = tid & 7;
    const int st = (tid >> 3) & 3;
    const int kw = tid >> 5;

    float acc[4][4];
#pragma unroll
    for (int i = 0; i < 4; ++i)
#pragma unroll
        for (int j = 0; j < 4; ++j) acc[i][j] = 0.0f;

    const float* wp = Wb + (size_t)cg * 1024 * 32 + (size_t)(kw * 128) * 32 + ct * 4;
    const float* ap = As + st * 4 * 1028 + kw * 128;

#pragma unroll 4
    for (int kk = 0; kk < 128; kk += 4) {
        float4 w0 = *(const float4*)(wp + (kk + 0) * 32);
        float4 w1 = *(const float4*)(wp + (kk + 1) * 32);
        float4 w2 = *(const float4*)(wp + (kk + 2) * 32);
        float4 w3 = *(const float4*)(wp + (kk + 3) * 32);
        float4 a0 = *(const float4*)(ap + 0 * 1028 + kk);
        float4 a1 = *(const float4*)(ap + 1 * 1028 + kk);
        float4 a2 = *(const float4*)(ap + 2 * 1028 + kk);
        float4 a3 = *(const float4*)(ap + 3 * 1028 + kk);
#define FMA_ROW(i, ai)                                              \
        acc[i][0] += ai.x * w0.x + ai.y * w1.x + ai.z * w2.x + ai.w * w3.x; \
        acc[i][1] += ai.x * w0.y + ai.y * w1.y + ai.z * w2.y + ai.w * w3.y; \
        acc[i][2] += ai.x * w0.z + ai.y * w1.z + ai.z * w2.z + ai.w * w3.z; \
        acc[i][3] += ai.x * w0.w + ai.y * w1.w + ai.z * w2.w + ai.w * w3.w;
        FMA_ROW(0, a0)
        FMA_ROW(1, a1)
        FMA_ROW(2, a2)
        FMA_ROW(3, a3)
#undef FMA_ROW
    }

#pragma unroll
    for (int i = 0; i < 4; ++i) {
        float4 v = make_float4(acc[i][0], acc[i][1], acc[i][2], acc[i][3]);
        *(float4*)(zpart + kw * 512 + (st * 4 + i) * 32 + ct * 4) = v;
    }
    __syncthreads();

    {
        int o = tid * 2;
        float z0 = 0.0f, z1 = 0.0f;
#pragma unroll
        for (int w = 0; w < 8; ++w) {
            float2 v = *(const float2*)(zpart + w * 512 + o);
            z0 += v.x; z1 += v.y;
        }
        *(float2*)(zred + o) = make_float2(z0, z1);
    }
    __syncthreads();

    if (tid < 128) {
        int s  = tid >> 3;
        int hc = tid & 7;
        int colb = cg * 8 + hc;
        float zf = zred[s * 32 + hc]       + bias[colb];
        float zi = zred[s * 32 + 8 + hc]   + bias[512 + colb];
        float zo = zred[s * 32 + 16 + hc]  + bias[1024 + colb];
        float zc = zred[s * 32 + 24 + hc]  + bias[1536 + colb];

        int cidx = (sg * 64 + cg) * 128 + tid;
        float cold = cbuf[cidx];
        float sf = 1.0f / (1.0f + expf(-zf));
        float si = 1.0f / (1.0f + expf(-zi));
        float so = 1.0f / (1.0f + expf(-zo));
        float cnew = sf * cold + si * zc;
        float h = so * cnew;
        cbuf[cidx] = cnew;

        hbw[(sg * 16 + s) * 512 + colb] = h;
        out[(size_t)(sg * 16 + s) * Tz * Hz + (size_t)t * Hz + colb] = h;
    }
}

static void run_legacy(const float* x, const float* W, const float* bias,
                       float* out, void* d_ws, hipStream_t stream) {
    char* ws = (char*)d_ws;
    float* Wb   = (float*)ws;
    float* hbuf = (float*)(ws + (size_t)WB_FLOATS * 4);
    float* cbuf = hbuf + 2 * HBUF_FLOATS;

    zero_ws<<<384, 256, 0, stream>>>(hbuf, 98304);
    prep_w<<<1024, 256, 0, stream>>>(W, Wb);

    for (int t = 0; t < Tz; ++t) {
        float* hr = hbuf + (t & 1) * HBUF_FLOATS;
        float* hw = hbuf + ((t + 1) & 1) * HBUF_FLOATS;
        lstm_step<<<dim3(64, 4), 256, 0, stream>>>(x, bias, Wb, hr, hw, cbuf, out, t);
    }
}

// ===================== launcher =====================
extern "C" void kernel_launch(void* const* d_in, const int* in_sizes, int n_in,
                              void* d_out, int out_size, void* d_ws, size_t ws_size,
                              hipStream_t stream) {
    const float* x    = (const float*)d_in[0];
    const float* W    = (const float*)d_in[1];
    const float* bias = (const float*)d_in[2];
    float* out = (float*)d_out;

    if (ws_size < FUSED_WS_BYTES) {      // cannot happen (6.2 KB); legacy safety net
        run_legacy(x, W, bias, out, d_ws, stream);
        return;
    }

    int* arrive = (int*)d_ws;
    float* zbuf = (float*)((char*)d_ws + ARR_INTS * 4);   // 16B-aligned

    zero_init<<<dim3((ARR_INTS + ZBUF_FL + 255) / 256), 256, 0, stream>>>(
        (int*)d_ws, ARR_INTS + ZBUF_FL);
    lstm_fused2<<<dim3(256), dim3(512), 0, stream>>>(x, W, bias, arrive, zbuf, out);
}

// Round 5
// 9622.762 us; speedup vs baseline: 2.7149x; 1.3091x over previous
//
#include <hip/hip_runtime.h>
#include <math.h>
#include <stdint.h>

// Problem: x[64][512][512] fp32, W[1024][2048] fp32, b[2048] fp32 -> out[64][512][512]
// z = [h,x]@W + b ; f,i,o,cb = split(z,4); c' = sig(f)*c + sig(i)*cb ; h' = sig(o)*c'
#define Bz 64
#define Tz 512
#define Dz 512
#define Hz 512

// block bx owns z-cols {g*512 + bx*2 + j} for g=0..3, j=0..1
__device__ __forceinline__ int wcol_of(int bx, int cc) {   // cc = g*2+j
    return (cc >> 1) * 512 + bx * 2 + (cc & 1);
}

// ===================== workspace (tiny) =====================
#define ARR_INTS 516
#define ZBUF_FL  512
#define FUSED_WS_BYTES ((size_t)(ARR_INTS + ZBUF_FL) * 4)

// ===================== LDS =====================
#define A_ST    1028                 /* row stride floats (16B-aligned rows)      */
#define A_FL    (16 * A_ST)          /* one quarter: 16 rows x 1024 k             */
#define ZSC_ST  132
#define POOL_FL (2 * A_FL + 8 * ZSC_ST)   /* 33952 fl = 135,808 B (< 160 KiB)     */

__global__ __launch_bounds__(256) void zero_init(int* __restrict__ p, int n) {
    int i = blockIdx.x * 256 + threadIdx.x;
    if (i < n) p[i] = 0;
}

__device__ __forceinline__ void gload_lds16(const float* g, float* l) {
    __builtin_amdgcn_global_load_lds((const __attribute__((address_space(1))) void*)g,
                                     (__attribute__((address_space(3))) void*)l,
                                     16, 0, 0);
}

// 16-lane (DPP-row) sum: xor1, xor2 quad_perms + row_ror 4, 8. Pure VALU.
template <int CTRL>
__device__ __forceinline__ float dppadd(float v) {
    int t = __builtin_amdgcn_update_dpp(0, __builtin_bit_cast(int, v),
                                        CTRL, 0xf, 0xf, true);
    return v + __builtin_bit_cast(float, t);
}
__device__ __forceinline__ float row16_sum(float v) {
    v = dppadd<0xB1>(v);    // quad_perm [1,0,3,2]  : xor 1
    v = dppadd<0x4E>(v);    // quad_perm [2,3,0,1]  : xor 2
    v = dppadd<0x124>(v);   // row_ror:4
    v = dppadd<0x128>(v);   // row_ror:8
    return v;
}

// stage x-half of one 16-row quarter; wave wid stages rows wid*2+{0,1}.
// Granule-XOR swizzle: LDS slot p of row r holds 16B-granule (p ^ rho), rho=(r>>2)&3;
// achieved by permuting the per-lane GLOBAL source (dest stays linear — rule #21).
__device__ __forceinline__ void stage_x2(float* __restrict__ Ab,
                                         const float* __restrict__ x,
                                         int t, int q, int wid, int lane) {
#pragma unroll
    for (int rr2 = 0; rr2 < 2; ++rr2) {
        int r = wid * 2 + rr2;
        int s = q * 16 + r;
        int rho = (r >> 2) & 3;
        const float* xs = x + (size_t)s * (Tz * Dz) + (size_t)t * Dz;
        float* arow = Ab + r * A_ST;
        int so = (lane ^ rho) << 2;
        gload_lds16(xs + so,       arow + 512);
        gload_lds16(xs + 256 + so, arow + 768);
    }
}
__device__ __forceinline__ void stage_h2(float* __restrict__ Ab,
                                         const float* __restrict__ out,
                                         const float* __restrict__ zbuf,
                                         int t, int q, int wid, int lane) {
#pragma unroll
    for (int rr2 = 0; rr2 < 2; ++rr2) {
        int r = wid * 2 + rr2;
        int s = q * 16 + r;
        int rho = (r >> 2) & 3;
        const float* hs = (t == 0) ? zbuf
                        : out + (size_t)s * (Tz * Hz) + (size_t)(t - 1) * Hz;
        float* arow = Ab + r * A_ST;
        int so = (lane ^ rho) << 2;
        gload_lds16(hs + so,       arow);
        gload_lds16(hs + 256 + so, arow + 256);
    }
}

// one quarter: counted-vmcnt wait -> barrier -> GEMM (W in regs, swizzled A reads)
// -> DPP in-row reduce -> float4 zsc partials -> barrier -> gates (QQ's 16 rows).
// Column order inside acc/zsc/wreg is c = j*4+g (so zsc IO is float4-contiguous).
template <int QQ, int VM>
__device__ __forceinline__ void quarter_body(const float* __restrict__ Ab,
                                             float* __restrict__ zsc,
                                             int tid, int lane, int wid, int rg, int kq,
                                             const float (&wreg)[8][8],
                                             const float (&bias_r)[4],
                                             float& c_reg, float& h_reg) {
    asm volatile("s_waitcnt vmcnt(%0)" :: "i"(VM) : "memory");
    __builtin_amdgcn_s_barrier();
    __builtin_amdgcn_sched_barrier(0);

    // ---- GEMM: 4 rows x 8 cols x 8 K per thread ----
    float acc[4][8];
    const int s0 = (2 * kq) ^ rg;          // swizzled granule slot of K-chunk lo
#pragma unroll
    for (int rr = 0; rr < 4; ++rr) {
        const float* ar = Ab + (rg * 4 + rr) * A_ST;
        float4 a0 = *(const float4*)(ar + (s0 << 2));
        float4 a1 = *(const float4*)(ar + ((s0 ^ 1) << 2));
#pragma unroll
        for (int c = 0; c < 8; ++c) {
            acc[rr][c] = a0.x * wreg[0][c] + a0.y * wreg[1][c]
                       + a0.z * wreg[2][c] + a0.w * wreg[3][c]
                       + a1.x * wreg[4][c] + a1.y * wreg[5][c]
                       + a1.z * wreg[6][c] + a1.w * wreg[7][c];
        }
    }

    // ---- in-row (16-lane) K-reduce on the VALU pipe ----
#pragma unroll
    for (int rr = 0; rr < 4; ++rr)
#pragma unroll
        for (int c = 0; c < 8; ++c)
            acc[rr][c] = row16_sum(acc[rr][c]);

    // ---- cross-wave partials: 8 writer lanes per row-group, float4 each ----
    if ((lane & 15) < 8) {
        int rr = (lane >> 1) & 3;
        int hf = lane & 1;
        *(float4*)(zsc + wid * ZSC_ST + (rg * 4 + rr) * 8 + hf * 4) =
            make_float4(acc[rr][hf * 4 + 0], acc[rr][hf * 4 + 1],
                        acc[rr][hf * 4 + 2], acc[rr][hf * 4 + 3]);
    }
    asm volatile("s_waitcnt lgkmcnt(0)" ::: "memory");
    __builtin_amdgcn_s_barrier();
    __builtin_amdgcn_sched_barrier(0);

    // ---- gates for this quarter's 16 rows ----
    if (tid < 128 && (tid >> 5) == QQ) {
        int lr = (tid >> 1) & 15, j = tid & 1;
        float zf = bias_r[0], zi = bias_r[1], zo = bias_r[2], zc = bias_r[3];
#pragma unroll
        for (int w = 0; w < 8; ++w) {
            float4 v = *(const float4*)(zsc + w * ZSC_ST + lr * 8 + j * 4);
            zf += v.x; zi += v.y; zo += v.z; zc += v.w;
        }
        float sf = 1.f / (1.f + expf(-zf));
        float si = 1.f / (1.f + expf(-zi));
        float so = 1.f / (1.f + expf(-zo));
        c_reg = sf * c_reg + si * zc;
        h_reg = so * c_reg;     // store deferred to end of step
    }
}

// --- persistent fused LSTM: 256 blocks (1/CU, 135.8 KB static LDS) x 512 thr ---
__global__ void __launch_bounds__(512) lstm_fused3(
        const float* __restrict__ x, const float* __restrict__ W,
        const float* __restrict__ bias, int* __restrict__ arrive,
        const float* __restrict__ zbuf, float* __restrict__ out) {
    __shared__ float pool[POOL_FL];
    float* A0  = pool;
    float* A1  = pool + A_FL;
    float* zsc = pool + 2 * A_FL;

    const int bx   = blockIdx.x;
    const int tid  = threadIdx.x;
    const int lane = tid & 63;
    const int wid  = tid >> 6;                  // 8 waves
    const int rg   = lane >> 4;                 // row-group (4 rows)
    const int kq   = wid * 16 + (lane & 15);    // 0..127, K-span 8
    const int koff = kq * 8;

    // ---- one-time: W slice into registers, (j,g)-permuted columns ----
    float wreg[8][8];
#pragma unroll
    for (int kk = 0; kk < 8; ++kk)
#pragma unroll
        for (int c = 0; c < 8; ++c) {
            int cc = ((c & 3) << 1) | (c >> 2);      // c=j*4+g -> cc=g*2+j
            wreg[kk][c] = W[(size_t)(koff + kk) * 2048 + wcol_of(bx, cc)];
        }

    float bias_r[4] = {0.f, 0.f, 0.f, 0.f};
    if (tid < 128) {
        int j = tid & 1;
#pragma unroll
        for (int g = 0; g < 4; ++g) bias_r[g] = bias[wcol_of(bx, g * 2 + j)];
    }
    const int s_own = tid >> 1, j_own = tid & 1;
    float c_reg = 0.f, h_reg = 0.f;

    for (int t = 0; t < Tz; ++t) {
        // ---- x of quarters 0,1: issued BEFORE the wait (no h dependency) ----
        stage_x2(A0, x, t, 0, wid, lane);
        stage_x2(A1, x, t, 1, wid, lane);

        // ---- wait for h_t (all blocks' step t-1 publishes) ----
        if (t > 0) {
            if (tid == 0) {
                int it = 0;
                while (__hip_atomic_load(arrive + (t - 1), __ATOMIC_RELAXED,
                                         __HIP_MEMORY_SCOPE_AGENT) < 256) {
                    __builtin_amdgcn_s_sleep(2);
                    if (++it > 20000) break;   // safety: wrong-results > hang
                }
            }
            __builtin_amdgcn_s_barrier();
            __builtin_amdgcn_sched_barrier(0);
        }

        stage_h2(A0, out, zbuf, t, 0, wid, lane);
        stage_h2(A1, out, zbuf, t, 1, wid, lane);

        // per-wave vmcnt ledger: x0(4) x1(4) h0(4) h1(4) | q2(8) | q3(8)
        quarter_body<0, 4>(A0, zsc, tid, lane, wid, rg, kq, wreg, bias_r, c_reg, h_reg);
        stage_x2(A0, x, t, 2, wid, lane);
        stage_h2(A0, out, zbuf, t, 2, wid, lane);
        quarter_body<1, 8>(A1, zsc, tid, lane, wid, rg, kq, wreg, bias_r, c_reg, h_reg);
        stage_x2(A1, x, t, 3, wid, lane);
        stage_h2(A1, out, zbuf, t, 3, wid, lane);
        quarter_body<2, 8>(A0, zsc, tid, lane, wid, rg, kq, wreg, bias_r, c_reg, h_reg);
        quarter_body<3, 0>(A1, zsc, tid, lane, wid, rg, kq, wreg, bias_r, c_reg, h_reg);

        // ---- publish h_{t+1} through out (agent-scope, no fences) ----
        if (tid < 128) {
            __hip_atomic_store(out + (size_t)s_own * (Tz * Hz) + (size_t)t * Hz
                                   + bx * 2 + j_own,
                               h_reg, __ATOMIC_RELAXED, __HIP_MEMORY_SCOPE_AGENT);
        }
        asm volatile("s_waitcnt vmcnt(0)" ::: "memory");
        __builtin_amdgcn_s_barrier();
        __builtin_amdgcn_sched_barrier(0);
        if (tid == 0)
            __hip_atomic_fetch_add(arrive + t, 1, __ATOMIC_RELAXED,
                                   __HIP_MEMORY_SCOPE_AGENT);
    }
}

// ===================== LEGACY PATH (verified fallback) =====================
#define WB_FLOATS   (64*1024*32)
#define HBUF_FLOATS (64*512)

__global__ __launch_bounds__(256) void zero_ws(float* __restrict__ p, int n) {
    int i = blockIdx.x * 256 + threadIdx.x;
    if (i < n) p[i] = 0.0f;
}

__global__ __launch_bounds__(256) void prep_w(const float* __restrict__ W,
                                              float* __restrict__ Wb) {
    int k = blockIdx.x;
    for (int it = 0; it < 8; ++it) {
        int col = it * 256 + threadIdx.x;
        float v = W[(size_t)k * 2048 + col];
        int g = col >> 9, rem = col & 511;
        int cg = rem >> 3, hc = rem & 7;
        int c = g * 8 + hc;
        Wb[((size_t)cg * 1024 + k) * 32 + c] = v;
    }
}

__global__ __launch_bounds__(256) void lstm_step(
    const float* __restrict__ x, const float* __restrict__ bias,
    const float* __restrict__ Wb, const float* __restrict__ hbr,
    float* __restrict__ hbw, float* __restrict__ cbuf,
    float* __restrict__ out, int t)
{
    const int cg  = blockIdx.x;
    const int sg  = blockIdx.y;
    const int tid = threadIdx.x;

    __shared__ float As[16 * 1028];
    __shared__ float zpart[8 * 512];
    __shared__ float zred[512];

    for (int it = 0; it < 16; ++it) {
        int fi = it * 256 + tid;
        int s  = fi >> 8;
        int k  = (fi & 255) * 4;
        const float* src;
        if (k < 512) src = hbr + (sg * 16 + s) * 512 + k;
        else         src = x + (size_t)(sg * 16 + s) * Tz * Dz + (size_t)t * Dz + (k - 512);
        float4 v = *(const float4*)src;
        *(float4*)(As + s * 1028 + k) = v;
    }
    __syncthreads();

    const int ct = tid & 7;
    const int st = (tid >> 3) & 3;
    const int kw = tid >> 5;

    float acc[4][4];
#pragma unroll
    for (int i = 0; i < 4; ++i)
#pragma unroll
        for (int j = 0; j < 4; ++j) acc[i][j] = 0.0f;

    const float* wp = Wb + (size_t)cg * 1024 * 32 + (size_t)(kw * 128) * 32 + ct * 4;
    const float* ap = As + st * 4 * 1028 + kw * 128;

#pragma unroll 4
    for (int kk = 0; kk < 128; kk += 4) {
        float4 w0 = *(const float4*)(wp + (kk + 0) * 32);
        float4 w1 = *(const float4*)(wp + (kk + 1) * 32);
        float4 w2 = *(const float4*)(wp + (kk + 2) * 32);
        float4 w3 = *(const float4*)(wp + (kk + 3) * 32);
        float4 a0 = *(const float4*)(ap + 0 * 1028 + kk);
        float4 a1 = *(const float4*)(ap + 1 * 1028 + kk);
        float4 a2 = *(const float4*)(ap + 2 * 1028 + kk);
        float4 a3 = *(const float4*)(ap + 3 * 1028 + kk);
#define FMA_ROW(i, ai)                                              \
        acc[i][0] += ai.x * w0.x + ai.y * w1.x + ai.z * w2.x + ai.w * w3.x; \
        acc[i][1] += ai.x * w0.y + ai.y * w1.y + ai.z * w2.y + ai.w * w3.y; \
        acc[i][2] += ai.x * w0.z + ai.y * w1.z + ai.z * w2.z + ai.w * w3.z; \
        acc[i][3] += ai.x * w0.w + ai.y * w1.w + ai.z * w2.w + ai.w * w3.w;
        FMA_ROW(0, a0)
        FMA_ROW(1, a1)
        FMA_ROW(2, a2)
        FMA_ROW(3, a3)
#undef FMA_ROW
    }

#pragma unroll
    for (int i = 0; i < 4; ++i) {
        float4 v = make_float4(acc[i][0], acc[i][1], acc[i][2], acc[i][3]);
        *(float4*)(zpart + kw * 512 + (st * 4 + i) * 32 + ct * 4) = v;
    }
    __syncthreads();

    {
        int o = tid * 2;
        float z0 = 0.0f, z1 = 0.0f;
#pragma unroll
        for (int w = 0; w < 8; ++w) {
            float2 v = *(const float2*)(zpart + w * 512 + o);
            z0 += v.x; z1 += v.y;
        }
        *(float2*)(zred + o) = make_float2(z0, z1);
    }
    __syncthreads();

    if (tid < 128) {
        int s  = tid >> 3;
        int hc = tid & 7;
        int colb = cg * 8 + hc;
        float zf = zred[s * 32 + hc]       + bias[colb];
        float zi = zred[s * 32 + 8 + hc]   + bias[512 + colb];
        float zo = zred[s * 32 + 16 + hc]  + bias[1024 + colb];
        float zc = zred[s * 32 + 24 + hc]  + bias[1536 + colb];

        int cidx = (sg * 64 + cg) * 128 + tid;
        float cold = cbuf[cidx];
        float sf = 1.0f / (1.0f + expf(-zf));
        float si = 1.0f / (1.0f + expf(-zi));
        float so = 1.0f / (1.0f + expf(-zo));
        float cnew = sf * cold + si * zc;
        float h = so * cnew;
        cbuf[cidx] = cnew;

        hbw[(sg * 16 + s) * 512 + colb] = h;
        out[(size_t)(sg * 16 + s) * Tz * Hz + (size_t)t * Hz + colb] = h;
    }
}

static void run_legacy(const float* x, const float* W, const float* bias,
                       float* out, void* d_ws, hipStream_t stream) {
    char* ws = (char*)d_ws;
    float* Wb   = (float*)ws;
    float* hbuf = (float*)(ws + (size_t)WB_FLOATS * 4);
    float* cbuf = hbuf + 2 * HBUF_FLOATS;

    zero_ws<<<384, 256, 0, stream>>>(hbuf, 98304);
    prep_w<<<1024, 256, 0, stream>>>(W, Wb);

    for (int t = 0; t < Tz; ++t) {
        float* hr = hbuf + (t & 1) * HBUF_FLOATS;
        float* hw = hbuf + ((t + 1) & 1) * HBUF_FLOATS;
        lstm_step<<<dim3(64, 4), 256, 0, stream>>>(x, bias, Wb, hr, hw, cbuf, out, t);
    }
}

// ===================== launcher =====================
extern "C" void kernel_launch(void* const* d_in, const int* in_sizes, int n_in,
                              void* d_out, int out_size, void* d_ws, size_t ws_size,
                              hipStream_t stream) {
    const float* x    = (const float*)d_in[0];
    const float* W    = (const float*)d_in[1];
    const float* bias = (const float*)d_in[2];
    float* out = (float*)d_out;

    if (ws_size < FUSED_WS_BYTES) {      // cannot happen (6.2 KB); legacy safety net
        run_legacy(x, W, bias, out, d_ws, stream);
        return;
    }

    int* arrive = (int*)d_ws;
    float* zbuf = (float*)((char*)d_ws + ARR_INTS * 4);   // 16B-aligned

    zero_init<<<dim3((ARR_INTS + ZBUF_FL + 255) / 256), 256, 0, stream>>>(
        (int*)d_ws, ARR_INTS + ZBUF_FL);
    lstm_fused3<<<dim3(256), dim3(512), 0, stream>>>(x, W, bias, arrive, zbuf, out);
}